// Round 6
// baseline (835.913 us; speedup 1.0000x reference)
//
#include <hip/hip_runtime.h>
#include <hip/hip_bf16.h>
#include <math.h>

#define NTOK 8192
#define DIM  1024
#define HDIM 512
#define KTOP 100
#define CHUNK 2048
#define KTH_RANK 2457   // threshold = 2457th-largest of Acmb == sort_asc[5735]

typedef float f32x4 __attribute__((ext_vector_type(4)));
typedef short bf16x8 __attribute__((ext_vector_type(8)));
typedef unsigned int u32;
typedef unsigned short u16;

// ---- monotone float<->uint key (order-preserving) ----
__device__ __forceinline__ unsigned key_of(float f) {
  unsigned u = __float_as_uint(f);
  return (u & 0x80000000u) ? ~u : (u | 0x80000000u);
}
__device__ __forceinline__ float float_of_key(unsigned key) {
  unsigned u = (key & 0x80000000u) ? (key ^ 0x80000000u) : ~key;
  return __uint_as_float(u);
}
// ---- bf16 round-to-nearest-even helpers ----
__device__ __forceinline__ u16 bf16_rn(float x) {
  unsigned u = __float_as_uint(x);
  return (u16)((u + 0x7FFFu + ((u >> 16) & 1u)) >> 16);
}
__device__ __forceinline__ float bf16f(u16 h) {
  return __uint_as_float(((unsigned)h) << 16);
}
// ---- async global->LDS 16B ----
__device__ __forceinline__ void gload16(const void* gptr, void* lptr) {
  __builtin_amdgcn_global_load_lds(
      (const __attribute__((address_space(1))) u32*)gptr,
      (__attribute__((address_space(3))) u32*)lptr, 16, 0, 0);
}

// ============================================================
// Unified split-bf16 NT GEMM, 2-phase double-buffered, BK=32.
// C = (Ahi+Alo).(Bhi+Blo)^T, A/B k-contiguous bf16 hi/lo pairs.
// 512 thr (8 waves 2x4), wave tile (FM*16) x 32, tile BM=FM*32 x 128.
// LDS rows are 64B (32 shorts); XOR swizzle quad ^= (row&3) applied on
// BOTH pre-swizzled global source (linear gload_lds dest) and frag reads
// -> balanced 8 lanes/quad-slot (conflict-free for b128).
// MODE 0: Cf = acc * rq[row]*rk[col]   (A-GEMM with folded normalization)
// MODE 1: t=tanh(acc+bias); Cf=t and Chi/Clo=split(t)   (q projection)
// MODE 2: t=tanh(acc+bias); Chi/Clo=split(t)            (k projection)
// ============================================================
template<int MODE, int FM>
__global__ __launch_bounds__(512, 4) void gemm_hl(
    const u16* __restrict__ Ahi, const u16* __restrict__ Alo,
    const u16* __restrict__ Bhi, const u16* __restrict__ Blo,
    float* __restrict__ Cf, u16* __restrict__ Chi, u16* __restrict__ Clo,
    const float* __restrict__ bias,
    const float* __restrict__ rq, const float* __restrict__ rk,
    int K, int ldc)
{
  constexpr int BM = FM * 32;
  constexpr int RT = 2 * BM + 256;   // concat rows: Ah[BM] Al[BM] Bh[128] Bl[128]
  constexpr int RPW = RT / 8;        // rows staged per wave
  constexpr int NI = RPW / 16;       // gload16 instrs per lane per k-step
  __shared__ __align__(16) short lds[2][RT * 32];

  const int tid = threadIdx.x, lane = tid & 63, wave = tid >> 6;
  const int wm = wave >> 2, wn = wave & 3;

  // XCD-bijective block swizzle (nwg % 8 == 0 for all grids used)
  const int nwg = gridDim.x * gridDim.y;
  const int lin = blockIdx.y * gridDim.x + blockIdx.x;
  const int cpx = nwg >> 3;
  const int swz = (lin & 7) * cpx + (lin >> 3);
  const int bx = swz % gridDim.x, by = swz / gridDim.x;
  const int bm = by * BM, bn = bx * 128;

  f32x4 acc[FM][2] = {};

  auto STAGE = [&](int buf, int k0) {
#pragma unroll
    for (int j = 0; j < NI; ++j) {
      int rg = wave * RPW + j * 16;            // wave-uniform 16-row group
      int r  = rg + (lane >> 2);               // per-lane row (same array)
      const u16* gp; size_t grow;
      if (rg < BM)                { gp = Ahi; grow = (size_t)(bm + r); }
      else if (rg < 2 * BM)       { gp = Alo; grow = (size_t)(bm + r - BM); }
      else if (rg < 2 * BM + 128) { gp = Bhi; grow = (size_t)(bn + r - 2 * BM); }
      else                        { gp = Blo; grow = (size_t)(bn + r - 2 * BM - 128); }
      int ks = k0 + (((lane & 3) ^ (r & 3)) << 3);   // pre-swizzled source quad
      gload16(gp + grow * (size_t)K + ks, &lds[buf][rg * 32]);
    }
  };

  STAGE(0, 0);
  __syncthreads();
  const int NT = K / 32;
  int cur = 0;
  for (int t = 0; t < NT; ++t) {
    if (t + 1 < NT) STAGE(cur ^ 1, (t + 1) * 32);   // prefetch next tile
    const short* L = lds[cur];
    const int qb = lane >> 4;
    bf16x8 ah[FM], al[FM], bh[2], bl[2];
#pragma unroll
    for (int m = 0; m < FM; ++m) {
      int r = wm * (FM * 16) + m * 16 + (lane & 15);
      int off = r * 32 + ((qb ^ (r & 3)) << 3);
      ah[m] = *(const bf16x8*)&L[off];
      al[m] = *(const bf16x8*)&L[BM * 32 + off];
    }
#pragma unroll
    for (int n = 0; n < 2; ++n) {
      int r = wn * 32 + n * 16 + (lane & 15);
      int off = r * 32 + ((qb ^ (r & 3)) << 3);
      bh[n] = *(const bf16x8*)&L[2 * BM * 32 + off];
      bl[n] = *(const bf16x8*)&L[(2 * BM + 128) * 32 + off];
    }
#pragma unroll
    for (int n = 0; n < 2; ++n)
#pragma unroll
      for (int m = 0; m < FM; ++m) {
        acc[m][n] = __builtin_amdgcn_mfma_f32_16x16x32_bf16(ah[m], bh[n], acc[m][n], 0, 0, 0);
        acc[m][n] = __builtin_amdgcn_mfma_f32_16x16x32_bf16(ah[m], bl[n], acc[m][n], 0, 0, 0);
        acc[m][n] = __builtin_amdgcn_mfma_f32_16x16x32_bf16(al[m], bh[n], acc[m][n], 0, 0, 0);
      }
    __syncthreads();   // drains vmcnt(0) (next-tile loads) + protects buffers
    cur ^= 1;
  }

  // ---- epilogue ----
#pragma unroll
  for (int m = 0; m < FM; ++m) {
    int rbase = bm + wm * (FM * 16) + m * 16 + (lane >> 4) * 4;
#pragma unroll
    for (int n = 0; n < 2; ++n) {
      int col = bn + wn * 32 + n * 16 + (lane & 15);
      if (MODE == 0) {
        float cs = rk[col];
#pragma unroll
        for (int r = 0; r < 4; ++r)
          Cf[(size_t)(rbase + r) * ldc + col] = acc[m][n][r] * rq[rbase + r] * cs;
      } else {
        float b = bias[col];
#pragma unroll
        for (int r = 0; r < 4; ++r) {
          size_t idx = (size_t)(rbase + r) * ldc + col;
          float t = tanhf(acc[m][n][r] + b);
          if (MODE == 1) Cf[idx] = t;
          u16 h = bf16_rn(t);
          Chi[idx] = h;
          Clo[idx] = bf16_rn(t - bf16f(h));
        }
      }
    }
  }
}

// ============================================================
// x [8192x1024] fp32 -> hi/lo bf16 (memory-bound)
// ============================================================
__global__ __launch_bounds__(256) void xsplit(
    const float* __restrict__ x, u16* __restrict__ hi, u16* __restrict__ lo)
{
  for (int i = blockIdx.x * 256 + threadIdx.x; i < NTOK * DIM / 4; i += gridDim.x * 256) {
    float4 v = ((const float4*)x)[i];
    ushort4 h, l;
    h.x = bf16_rn(v.x); l.x = bf16_rn(v.x - bf16f(h.x));
    h.y = bf16_rn(v.y); l.y = bf16_rn(v.y - bf16f(h.y));
    h.z = bf16_rn(v.z); l.z = bf16_rn(v.z - bf16f(h.z));
    h.w = bf16_rn(v.w); l.w = bf16_rn(v.w - bf16f(h.w));
    ((ushort4*)hi)[i] = h;
    ((ushort4*)lo)[i] = l;
  }
}

// ============================================================
// W [K=1024][N=512] fp32 -> WT hi/lo [512][1024] bf16 (tiled transpose)
// ============================================================
__global__ __launch_bounds__(256) void wt_cast(
    const float* __restrict__ W, u16* __restrict__ Thi, u16* __restrict__ Tlo)
{
  __shared__ float t[32][33];
  const int bx = blockIdx.x, by = blockIdx.y;
  const int r = threadIdx.x >> 5, c = threadIdx.x & 31;
#pragma unroll
  for (int i = 0; i < 4; ++i)
    t[r + i * 8][c] = W[(size_t)(by * 32 + r + i * 8) * HDIM + bx * 32 + c];
  __syncthreads();
#pragma unroll
  for (int i = 0; i < 4; ++i) {
    int n = bx * 32 + r + i * 8, k = by * 32 + c;
    float v = t[c][r + i * 8];
    u16 h = bf16_rn(v);
    Thi[(size_t)n * DIM + k] = h;
    Tlo[(size_t)n * DIM + k] = bf16_rn(v - bf16f(h));
  }
}

// ============================================================
// Inverse row norms of the hi/lo split pairs.
// blocks 0..2047 -> q rows, 2048..4095 -> k rows; 4 rows/block (1 wave/row).
// ============================================================
__global__ __launch_bounds__(256) void rownorm_inv(
    const u16* __restrict__ qh, const u16* __restrict__ ql,
    const u16* __restrict__ kh, const u16* __restrict__ kl,
    float* __restrict__ rq, float* __restrict__ rk)
{
  const int half = blockIdx.x >> 11;
  const int row = (blockIdx.x & 2047) * 4 + (threadIdx.x >> 6);
  const int lane = threadIdx.x & 63;
  const u16* hi = half ? kh : qh;
  const u16* lo = half ? kl : ql;
  size_t base = (size_t)row * HDIM + lane * 8;
  ushort4 h0 = *(const ushort4*)&hi[base], h1 = *(const ushort4*)&hi[base + 4];
  ushort4 l0 = *(const ushort4*)&lo[base], l1 = *(const ushort4*)&lo[base + 4];
  float f[8] = {bf16f(h0.x)+bf16f(l0.x), bf16f(h0.y)+bf16f(l0.y),
                bf16f(h0.z)+bf16f(l0.z), bf16f(h0.w)+bf16f(l0.w),
                bf16f(h1.x)+bf16f(l1.x), bf16f(h1.y)+bf16f(l1.y),
                bf16f(h1.z)+bf16f(l1.z), bf16f(h1.w)+bf16f(l1.w)};
  float ss = 0.f;
#pragma unroll
  for (int j = 0; j < 8; ++j) ss += f[j] * f[j];
#pragma unroll
  for (int off = 32; off > 0; off >>= 1) ss += __shfl_xor(ss, off);
  if (lane == 0) {
    float r = 1.0f / fmaxf(sqrtf(ss), 1e-12f);
    (half ? rk : rq)[row] = r;
  }
}

// ============================================================
// Per-row exact top-100.  Pass 3 (top byte) over the full row with
// wave-aggregated histogram atomics, compact candidates, passes 2..0 on
// the compacted set, collect, bitonic sort, dot with WA.
// One block (1024 thr) per row.
// ============================================================
__global__ __launch_bounds__(1024) void topk_acmb(
    const float* __restrict__ Arows, const float* __restrict__ WA_w,
    const float* __restrict__ WA_b, float* __restrict__ Acmb, int row_base)
{
  __shared__ unsigned rowk[NTOK];       // 32 KB
  __shared__ unsigned cmpk[4096];       // 16 KB
  __shared__ unsigned hist[256];
  __shared__ unsigned sufs[256];
  __shared__ unsigned cand[128];
  __shared__ float red[128];
  __shared__ unsigned s_prefix, s_need, s_ncand, s_cc, s_cg, s_ce;

  const int tid = threadIdx.x;
  const float4* src = (const float4*)(Arows + (size_t)blockIdx.x * NTOK);
#pragma unroll
  for (int it = 0; it < 2; ++it) {
    int i = tid + it * 1024;
    float4 v = src[i];
    *(uint4*)&rowk[i * 4] =
        make_uint4(key_of(v.x), key_of(v.y), key_of(v.z), key_of(v.w));
  }
  if (tid == 0) { s_prefix = 0u; s_need = KTOP; s_ncand = 0u; s_cc = 0u; s_cg = 0u; s_ce = 0u; }
  if (tid < 256) hist[tid] = 0u;
  __syncthreads();

  // ---- pass 3: top byte, ballot-aggregated atomics ----
#pragma unroll
  for (int it = 0; it < 8; ++it) {
    unsigned bin = rowk[tid + it * 1024] >> 24;
    unsigned long long act = __ballot(true);
    while (act) {
      int leader = __ffsll(act) - 1;
      unsigned lbin = __shfl(bin, leader);
      unsigned long long match = __ballot(bin == lbin) & act;
      if ((tid & 63) == leader) atomicAdd(&hist[lbin], (unsigned)__popcll(match));
      act &= ~match;
    }
  }
  __syncthreads();
  if (tid < 256) sufs[tid] = hist[tid];
  __syncthreads();
  for (int off = 1; off < 256; off <<= 1) {
    unsigned add = 0u;
    if (tid < 256 && tid + off < 256) add = sufs[tid + off];
    __syncthreads();
    if (tid < 256) sufs[tid] += add;
    __syncthreads();
  }
  if (tid < 256) {
    unsigned above = (tid == 255) ? 0u : sufs[tid + 1];
    if (sufs[tid] >= KTOP && above < KTOP) {
      s_prefix = (unsigned)tid << 24;
      s_need   = KTOP - above;
      s_ncand  = sufs[tid];
    }
  }
  __syncthreads();
  const unsigned d3 = s_prefix >> 24;
  const unsigned ncand = s_ncand;
  const bool compact = (ncand <= 4096u);

  if (compact) {
#pragma unroll
    for (int it = 0; it < 8; ++it) {
      unsigned key = rowk[tid + it * 1024];
      if ((key >> 24) >= d3) cmpk[atomicAdd(&s_cc, 1u)] = key;
    }
  }
  __syncthreads();

  for (int pass = 2; pass >= 0; --pass) {
    if (tid < 256) hist[tid] = 0u;
    __syncthreads();
    unsigned pref  = s_prefix;
    unsigned pmask = 0xFFFFFFFFu << ((pass + 1) * 8);
    if (compact) {
      for (int i = tid; i < (int)ncand; i += 1024) {
        unsigned key = cmpk[i];
        if ((key & pmask) == pref)
          atomicAdd(&hist[(key >> (pass * 8)) & 255u], 1u);
      }
    } else {
      for (int it = 0; it < 8; ++it) {
        unsigned key = rowk[tid + it * 1024];
        if ((key & pmask) == pref)
          atomicAdd(&hist[(key >> (pass * 8)) & 255u], 1u);
      }
    }
    __syncthreads();
    if (tid < 256) sufs[tid] = hist[tid];
    __syncthreads();
    for (int off = 1; off < 256; off <<= 1) {
      unsigned add = 0u;
      if (tid < 256 && tid + off < 256) add = sufs[tid + off];
      __syncthreads();
      if (tid < 256) sufs[tid] += add;
      __syncthreads();
    }
    unsigned need = s_need;
    __syncthreads();
    if (tid < 256) {
      unsigned above = (tid == 255) ? 0u : sufs[tid + 1];
      if (sufs[tid] >= need && above < need) {
        s_prefix = pref | ((unsigned)tid << (pass * 8));
        s_need   = need - above;
      }
    }
    __syncthreads();
  }
  const unsigned kth = s_prefix, needEq = s_need;

  if (tid < 128) cand[tid] = 0u;
  __syncthreads();
  if (compact) {
    for (int i = tid; i < (int)ncand; i += 1024) {
      unsigned key = cmpk[i];
      if (key > kth) cand[atomicAdd(&s_cg, 1u)] = key;
    }
  } else {
    for (int it = 0; it < 8; ++it) {
      unsigned key = rowk[tid + it * 1024];
      if (key > kth) cand[atomicAdd(&s_cg, 1u)] = key;
    }
  }
  __syncthreads();
  const unsigned nAbove = s_cg;
  if (compact) {
    for (int i = tid; i < (int)ncand; i += 1024) {
      unsigned key = cmpk[i];
      if (key == kth) {
        unsigned p = atomicAdd(&s_ce, 1u);
        if (p < needEq) cand[nAbove + p] = key;
      }
    }
  } else {
    for (int it = 0; it < 8; ++it) {
      unsigned key = rowk[tid + it * 1024];
      if (key == kth) {
        unsigned p = atomicAdd(&s_ce, 1u);
        if (p < needEq) cand[nAbove + p] = key;
      }
    }
  }
  __syncthreads();

  for (int k = 2; k <= 128; k <<= 1)
    for (int j = k >> 1; j > 0; j >>= 1) {
      if (tid < 128) {
        int i = tid, ixj = i ^ j;
        if (ixj > i) {
          unsigned a = cand[i], b = cand[ixj];
          if ((a > b) == ((i & k) == 0)) { cand[i] = b; cand[ixj] = a; }
        }
      }
      __syncthreads();
    }

  float term = 0.0f;
  if (tid < KTOP) {
    float a1 = float_of_key(cand[28 + tid]);
    term = a1 * WA_w[tid] + a1 * a1 * WA_w[KTOP + tid];
  }
  if (tid < 128) red[tid] = term;
  __syncthreads();
  for (int off = 64; off > 0; off >>= 1) {
    if (tid < off) red[tid] += red[tid + off];
    __syncthreads();
  }
  if (tid == 0) Acmb[row_base + (int)blockIdx.x] = -(red[0] + WA_b[0]);
}

// ============================================================
// Threshold (rank select) + softmax over N -> Aw in out[1..N]
// ============================================================
__global__ __launch_bounds__(1024) void thr_softmax(
    const float* __restrict__ Acmb, float* __restrict__ out)
{
  __shared__ float vals[NTOK];
  __shared__ unsigned hist[256];
  __shared__ unsigned sufs[256];
  __shared__ float red[1024];
  __shared__ unsigned s_prefix, s_need;
  const int tid = threadIdx.x;
#pragma unroll
  for (int s = 0; s < 8; ++s) vals[tid + s * 1024] = Acmb[tid + s * 1024];
  if (tid == 0) { s_prefix = 0u; s_need = KTH_RANK; }
  __syncthreads();

  for (int pass = 3; pass >= 0; --pass) {
    if (tid < 256) hist[tid] = 0u;
    __syncthreads();
    unsigned pref  = s_prefix;
    unsigned pmask = (pass == 3) ? 0u : (0xFFFFFFFFu << ((pass + 1) * 8));
#pragma unroll
    for (int s = 0; s < 8; ++s) {
      unsigned key = key_of(vals[tid + s * 1024]);
      if ((key & pmask) == pref)
        atomicAdd(&hist[(key >> (pass * 8)) & 255u], 1u);
    }
    __syncthreads();
    if (tid < 256) sufs[tid] = hist[tid];
    __syncthreads();
    for (int off = 1; off < 256; off <<= 1) {
      unsigned add = 0u;
      if (tid < 256 && tid + off < 256) add = sufs[tid + off];
      __syncthreads();
      if (tid < 256) sufs[tid] += add;
      __syncthreads();
    }
    unsigned need = s_need;
    __syncthreads();
    if (tid < 256) {
      unsigned above = (tid == 255) ? 0u : sufs[tid + 1];
      if (sufs[tid] >= need && above < need) {
        s_prefix = pref | ((unsigned)tid << (pass * 8));
        s_need   = need - above;
      }
    }
    __syncthreads();
  }
  const float thre = float_of_key(s_prefix);

  float loc[8]; float mx = -1e30f;
#pragma unroll
  for (int s = 0; s < 8; ++s) {
    float v = vals[tid + s * 1024];
    v = (v > thre) ? v : 0.0f;
    loc[s] = v; mx = fmaxf(mx, v);
  }
  red[tid] = mx; __syncthreads();
  for (int off = 512; off > 0; off >>= 1) {
    if (tid < off) red[tid] = fmaxf(red[tid], red[tid + off]);
    __syncthreads();
  }
  float m = red[0]; __syncthreads();
  float sm = 0.0f;
#pragma unroll
  for (int s = 0; s < 8; ++s) sm += expf(loc[s] - m);
  red[tid] = sm; __syncthreads();
  for (int off = 512; off > 0; off >>= 1) {
    if (tid < off) red[tid] += red[tid + off];
    __syncthreads();
  }
  float Z = red[0];
#pragma unroll
  for (int s = 0; s < 8; ++s)
    out[1 + tid + s * 1024] = expf(loc[s] - m) / Z;
}

// ============================================================
__global__ __launch_bounds__(256) void z_partial(
    const float* __restrict__ aw, const float* __restrict__ query,
    float* __restrict__ zpart)
{
  const int g = blockIdx.x, t = threadIdx.x;
  float a0 = 0.f, a1 = 0.f;
  for (int r = 0; r < 64; ++r) {
    int n = g * 64 + r;
    float w = aw[n];
    const float* q = query + (size_t)n * HDIM;
    a0 = fmaf(w, q[t],       a0);
    a1 = fmaf(w, q[t + 256], a1);
  }
  zpart[(size_t)g * HDIM + t]       = a0;
  zpart[(size_t)g * HDIM + t + 256] = a1;
}

__global__ __launch_bounds__(512) void finalize(
    const float* __restrict__ zpart, const float* __restrict__ cls_w,
    const float* __restrict__ cls_b, float* __restrict__ out)
{
  __shared__ float red[512];
  const int t = threadIdx.x;
  float s = 0.f;
  for (int g = 0; g < 128; ++g) s += zpart[(size_t)g * HDIM + t];
  red[t] = s * cls_w[t];
  __syncthreads();
  for (int off = 256; off > 0; off >>= 1) {
    if (t < off) red[t] += red[t + off];
    __syncthreads();
  }
  if (t == 0) out[0] = red[0] + cls_b[0];
}

// ============================================================
extern "C" void kernel_launch(void* const* d_in, const int* in_sizes, int n_in,
                              void* d_out, int out_size, void* d_ws, size_t ws_size,
                              hipStream_t stream) {
  (void)in_sizes; (void)n_in; (void)out_size; (void)ws_size;
  const float* x_q   = (const float*)d_in[0];
  const float* x_k   = (const float*)d_in[1];
  const float* WQ_w  = (const float*)d_in[2];
  const float* WQ_b  = (const float*)d_in[3];
  const float* WK_w  = (const float*)d_in[4];
  const float* WK_b  = (const float*)d_in[5];
  const float* WA_w  = (const float*)d_in[6];
  const float* WA_b  = (const float*)d_in[7];
  const float* cls_w = (const float*)d_in[8];
  const float* cls_b = (const float*)d_in[9];
  float* out = (float*)d_out;
  char* base = (char*)d_ws;
  const size_t MB = 1u << 20;

  // ws_size = 256 MiB (poison fill = 262144 KB). Layout ~150 MB:
  float* query = (float*)(base);               // 0..16 fp32 tanh(xWq+b)
  u16* qh      = (u16*)(base + 16 * MB);       // 16..24 (unnormalized split)
  u16* ql      = (u16*)(base + 24 * MB);       // 24..32
  u16* kh      = (u16*)(base + 32 * MB);       // 32..40
  u16* kl      = (u16*)(base + 40 * MB);       // 40..48
  u16* xs_hi   = (u16*)(base + 48 * MB);       // 48..64 (x split, dead after proj)
  u16* xs_lo   = (u16*)(base + 64 * MB);       // 64..80
  float* Ach   = (float*)(base + 80 * MB);     // 80..144 (A chunk, 64 MB)
  u16* wt_hi   = (u16*)(base + 144 * MB);      // 144..145
  u16* wt_lo   = (u16*)(base + 145 * MB);      // 145..146
  float* rq    = (float*)(base + 146 * MB);    // 32 KB
  float* rk    = (float*)(base + 146 * MB + 65536);
  float* Acmb  = (float*)(base + 147 * MB);    // 32 KB
  float* zpart = (float*)(base + 147 * MB + 65536);  // 256 KB

  dim3 b256(256), b512(512);
  dim3 gproj(HDIM / 128, NTOK / 64);           // 4 x 128 = 512 blocks (FM=2)
  dim3 gchunk(NTOK / 128, CHUNK / 128);        // 64 x 16 = 1024 blocks (FM=4)

  // --- projections: query (fp32 + split) and k (split only) ---
  wt_cast<<<dim3(16, 32), b256, 0, stream>>>(WQ_w, wt_hi, wt_lo);
  xsplit<<<2048, b256, 0, stream>>>(x_q, xs_hi, xs_lo);
  gemm_hl<1, 2><<<gproj, b512, 0, stream>>>(xs_hi, xs_lo, wt_hi, wt_lo,
      query, qh, ql, WQ_b, nullptr, nullptr, DIM, HDIM);
  wt_cast<<<dim3(16, 32), b256, 0, stream>>>(WK_w, wt_hi, wt_lo);
  xsplit<<<2048, b256, 0, stream>>>(x_k, xs_hi, xs_lo);
  gemm_hl<2, 2><<<gproj, b512, 0, stream>>>(xs_hi, xs_lo, wt_hi, wt_lo,
      nullptr, kh, kl, WK_b, nullptr, nullptr, DIM, HDIM);
  // --- inverse row norms (normalization folded into A epilogue) ---
  rownorm_inv<<<4096, b256, 0, stream>>>(qh, ql, kh, kl, rq, rk);
  // --- A chunks (scaled in epilogue) + fused exact top-100 -> Acmb ---
  for (int c = 0; c < NTOK / CHUNK; ++c) {
    gemm_hl<0, 4><<<gchunk, b512, 0, stream>>>(
        qh + (size_t)c * CHUNK * HDIM, ql + (size_t)c * CHUNK * HDIM,
        kh, kl, Ach, nullptr, nullptr, nullptr, rq + c * CHUNK, rk, HDIM, NTOK);
    topk_acmb<<<CHUNK, dim3(1024), 0, stream>>>(Ach, WA_w, WA_b, Acmb, c * CHUNK);
  }
  // --- threshold + softmax -> Aw ---
  thr_softmax<<<1, dim3(1024), 0, stream>>>(Acmb, out);
  // --- z = Aw @ query ; Y -> out[0] ---
  z_partial<<<128, b256, 0, stream>>>(out + 1, query, zpart);
  finalize<<<1, dim3(512), 0, stream>>>(zpart, cls_w, cls_b, out);
}

// Round 7
// 568.525 us; speedup vs baseline: 1.4703x; 1.4703x over previous
//
#include <hip/hip_runtime.h>
#include <hip/hip_bf16.h>
#include <math.h>

#define NTOK 8192
#define DIM  1024
#define HDIM 512
#define KTOP 100
#define CHUNK 2048
#define KTH_RANK 2457   // threshold = 2457th-largest of Acmb == sort_asc[5735]
#define EQCAP 2048
#define PADK 0x3FFFFFFFu   // key_of(-2.0f): below every real key (|A|<=1)

typedef float f32x4 __attribute__((ext_vector_type(4)));
typedef short bf16x8 __attribute__((ext_vector_type(8)));
typedef unsigned int u32;
typedef unsigned short u16;

// ---- monotone float<->uint key (order-preserving) ----
__device__ __forceinline__ unsigned key_of(float f) {
  unsigned u = __float_as_uint(f);
  return (u & 0x80000000u) ? ~u : (u | 0x80000000u);
}
__device__ __forceinline__ float float_of_key(unsigned key) {
  unsigned u = (key & 0x80000000u) ? (key ^ 0x80000000u) : ~key;
  return __uint_as_float(u);
}
// ---- bf16 round-to-nearest-even helpers ----
__device__ __forceinline__ u16 bf16_rn(float x) {
  unsigned u = __float_as_uint(x);
  return (u16)((u + 0x7FFFu + ((u >> 16) & 1u)) >> 16);
}
__device__ __forceinline__ float bf16f(u16 h) {
  return __uint_as_float(((unsigned)h) << 16);
}
// ---- async global->LDS 16B ----
__device__ __forceinline__ void gload16(const void* gptr, void* lptr) {
  __builtin_amdgcn_global_load_lds(
      (const __attribute__((address_space(1))) u32*)gptr,
      (__attribute__((address_space(3))) u32*)lptr, 16, 0, 0);
}

// ============================================================
// Unified split-bf16 NT GEMM, 2-phase double-buffered, BK=32.
// (unchanged from previous round)
// ============================================================
template<int MODE, int FM>
__global__ __launch_bounds__(512, 4) void gemm_hl(
    const u16* __restrict__ Ahi, const u16* __restrict__ Alo,
    const u16* __restrict__ Bhi, const u16* __restrict__ Blo,
    float* __restrict__ Cf, u16* __restrict__ Chi, u16* __restrict__ Clo,
    const float* __restrict__ bias,
    const float* __restrict__ rq, const float* __restrict__ rk,
    int K, int ldc)
{
  constexpr int BM = FM * 32;
  constexpr int RT = 2 * BM + 256;
  constexpr int RPW = RT / 8;
  constexpr int NI = RPW / 16;
  __shared__ __align__(16) short lds[2][RT * 32];

  const int tid = threadIdx.x, lane = tid & 63, wave = tid >> 6;
  const int wm = wave >> 2, wn = wave & 3;

  const int nwg = gridDim.x * gridDim.y;
  const int lin = blockIdx.y * gridDim.x + blockIdx.x;
  const int cpx = nwg >> 3;
  const int swz = (lin & 7) * cpx + (lin >> 3);
  const int bx = swz % gridDim.x, by = swz / gridDim.x;
  const int bm = by * BM, bn = bx * 128;

  f32x4 acc[FM][2] = {};

  auto STAGE = [&](int buf, int k0) {
#pragma unroll
    for (int j = 0; j < NI; ++j) {
      int rg = wave * RPW + j * 16;
      int r  = rg + (lane >> 2);
      const u16* gp; size_t grow;
      if (rg < BM)                { gp = Ahi; grow = (size_t)(bm + r); }
      else if (rg < 2 * BM)       { gp = Alo; grow = (size_t)(bm + r - BM); }
      else if (rg < 2 * BM + 128) { gp = Bhi; grow = (size_t)(bn + r - 2 * BM); }
      else                        { gp = Blo; grow = (size_t)(bn + r - 2 * BM - 128); }
      int ks = k0 + (((lane & 3) ^ (r & 3)) << 3);
      gload16(gp + grow * (size_t)K + ks, &lds[buf][rg * 32]);
    }
  };

  STAGE(0, 0);
  __syncthreads();
  const int NT = K / 32;
  int cur = 0;
  for (int t = 0; t < NT; ++t) {
    if (t + 1 < NT) STAGE(cur ^ 1, (t + 1) * 32);
    const short* L = lds[cur];
    const int qb = lane >> 4;
    bf16x8 ah[FM], al[FM], bh[2], bl[2];
#pragma unroll
    for (int m = 0; m < FM; ++m) {
      int r = wm * (FM * 16) + m * 16 + (lane & 15);
      int off = r * 32 + ((qb ^ (r & 3)) << 3);
      ah[m] = *(const bf16x8*)&L[off];
      al[m] = *(const bf16x8*)&L[BM * 32 + off];
    }
#pragma unroll
    for (int n = 0; n < 2; ++n) {
      int r = wn * 32 + n * 16 + (lane & 15);
      int off = r * 32 + ((qb ^ (r & 3)) << 3);
      bh[n] = *(const bf16x8*)&L[2 * BM * 32 + off];
      bl[n] = *(const bf16x8*)&L[(2 * BM + 128) * 32 + off];
    }
#pragma unroll
    for (int n = 0; n < 2; ++n)
#pragma unroll
      for (int m = 0; m < FM; ++m) {
        acc[m][n] = __builtin_amdgcn_mfma_f32_16x16x32_bf16(ah[m], bh[n], acc[m][n], 0, 0, 0);
        acc[m][n] = __builtin_amdgcn_mfma_f32_16x16x32_bf16(ah[m], bl[n], acc[m][n], 0, 0, 0);
        acc[m][n] = __builtin_amdgcn_mfma_f32_16x16x32_bf16(al[m], bh[n], acc[m][n], 0, 0, 0);
      }
    __syncthreads();
    cur ^= 1;
  }

#pragma unroll
  for (int m = 0; m < FM; ++m) {
    int rbase = bm + wm * (FM * 16) + m * 16 + (lane >> 4) * 4;
#pragma unroll
    for (int n = 0; n < 2; ++n) {
      int col = bn + wn * 32 + n * 16 + (lane & 15);
      if (MODE == 0) {
        float cs = rk[col];
#pragma unroll
        for (int r = 0; r < 4; ++r)
          Cf[(size_t)(rbase + r) * ldc + col] = acc[m][n][r] * rq[rbase + r] * cs;
      } else {
        float b = bias[col];
#pragma unroll
        for (int r = 0; r < 4; ++r) {
          size_t idx = (size_t)(rbase + r) * ldc + col;
          float t = tanhf(acc[m][n][r] + b);
          if (MODE == 1) Cf[idx] = t;
          u16 h = bf16_rn(t);
          Chi[idx] = h;
          Clo[idx] = bf16_rn(t - bf16f(h));
        }
      }
    }
  }
}

// ============================================================
__global__ __launch_bounds__(256) void xsplit(
    const float* __restrict__ x, u16* __restrict__ hi, u16* __restrict__ lo)
{
  for (int i = blockIdx.x * 256 + threadIdx.x; i < NTOK * DIM / 4; i += gridDim.x * 256) {
    float4 v = ((const float4*)x)[i];
    ushort4 h, l;
    h.x = bf16_rn(v.x); l.x = bf16_rn(v.x - bf16f(h.x));
    h.y = bf16_rn(v.y); l.y = bf16_rn(v.y - bf16f(h.y));
    h.z = bf16_rn(v.z); l.z = bf16_rn(v.z - bf16f(h.z));
    h.w = bf16_rn(v.w); l.w = bf16_rn(v.w - bf16f(h.w));
    ((ushort4*)hi)[i] = h;
    ((ushort4*)lo)[i] = l;
  }
}

// ============================================================
__global__ __launch_bounds__(256) void wt_cast(
    const float* __restrict__ W, u16* __restrict__ Thi, u16* __restrict__ Tlo)
{
  __shared__ float t[32][33];
  const int bx = blockIdx.x, by = blockIdx.y;
  const int r = threadIdx.x >> 5, c = threadIdx.x & 31;
#pragma unroll
  for (int i = 0; i < 4; ++i)
    t[r + i * 8][c] = W[(size_t)(by * 32 + r + i * 8) * HDIM + bx * 32 + c];
  __syncthreads();
#pragma unroll
  for (int i = 0; i < 4; ++i) {
    int n = bx * 32 + r + i * 8, k = by * 32 + c;
    float v = t[c][r + i * 8];
    u16 h = bf16_rn(v);
    Thi[(size_t)n * DIM + k] = h;
    Tlo[(size_t)n * DIM + k] = bf16_rn(v - bf16f(h));
  }
}

// ============================================================
__global__ __launch_bounds__(256) void rownorm_inv(
    const u16* __restrict__ qh, const u16* __restrict__ ql,
    const u16* __restrict__ kh, const u16* __restrict__ kl,
    float* __restrict__ rq, float* __restrict__ rk)
{
  const int half = blockIdx.x >> 11;
  const int row = (blockIdx.x & 2047) * 4 + (threadIdx.x >> 6);
  const int lane = threadIdx.x & 63;
  const u16* hi = half ? kh : qh;
  const u16* lo = half ? kl : ql;
  size_t base = (size_t)row * HDIM + lane * 8;
  ushort4 h0 = *(const ushort4*)&hi[base], h1 = *(const ushort4*)&hi[base + 4];
  ushort4 l0 = *(const ushort4*)&lo[base], l1 = *(const ushort4*)&lo[base + 4];
  float f[8] = {bf16f(h0.x)+bf16f(l0.x), bf16f(h0.y)+bf16f(l0.y),
                bf16f(h0.z)+bf16f(l0.z), bf16f(h0.w)+bf16f(l0.w),
                bf16f(h1.x)+bf16f(l1.x), bf16f(h1.y)+bf16f(l1.y),
                bf16f(h1.z)+bf16f(l1.z), bf16f(h1.w)+bf16f(l1.w)};
  float ss = 0.f;
#pragma unroll
  for (int j = 0; j < 8; ++j) ss += f[j] * f[j];
#pragma unroll
  for (int off = 32; off > 0; off >>= 1) ss += __shfl_xor(ss, off);
  if (lane == 0) {
    float r = 1.0f / fmaxf(sqrtf(ss), 1e-12f);
    (half ? rk : rq)[row] = r;
  }
}

// ============================================================
// Per-row exact top-100, barrier-minimized.
// 256 thr/block, one block per row, keys in registers (32/thread).
// 12-bit histogram (4096 bins packed 2/u32) -> wave-scan suffix scan ->
// boundary bin+need; optional 2nd 12-bit level if the boundary bin is
// huge (cannot trigger on this data, kept for safety).  Collect ~100+cb
// candidates to small LDS; wave0 finishes with an in-register 128-wide
// cross-lane bitonic sort (shfl_xor, no barriers) and the WA dot.
// ============================================================
__global__ __launch_bounds__(256) void topk_acmb(
    const float* __restrict__ Arows, const float* __restrict__ WA_w,
    const float* __restrict__ WA_b, float* __restrict__ Acmb, int row_base)
{
  __shared__ u32 hist[2048];      // 4096 bins, 2 x 16-bit counts per u32
  __shared__ u32 eqbuf[EQCAP];
  __shared__ u32 grbuf[128];
  __shared__ u32 tsum[256], tabove[256];
  __shared__ u32 s_b, s_need, s_cb, s_b2, s_need2, s_cb2, s_cg, s_ce;

  const int tid = threadIdx.x;
  const float4* src = (const float4*)(Arows + (size_t)blockIdx.x * NTOK);

  for (int i = tid; i < 2048; i += 256) hist[i] = 0u;
  if (tid == 0) { s_cg = 0u; s_ce = 0u; }

  // ---- load 32 values (coalesced) -> keys in registers ----
  u32 keys[32];
#pragma unroll
  for (int i = 0; i < 8; ++i) {
    float4 v = src[i * 256 + tid];
    keys[i * 4 + 0] = key_of(v.x);
    keys[i * 4 + 1] = key_of(v.y);
    keys[i * 4 + 2] = key_of(v.z);
    keys[i * 4 + 3] = key_of(v.w);
  }
  __syncthreads();   // hist zero visible

  // ---- level-1 histogram: top 12 bits ----
#pragma unroll
  for (int j = 0; j < 32; ++j) {
    u32 bin = keys[j] >> 20;
    atomicAdd(&hist[bin >> 1], (bin & 1) ? 0x10000u : 1u);
  }
  __syncthreads();

  // ---- suffix scan over 4096 bins -> boundary bin, need, bin count ----
  auto scan12 = [&](u32 needK, u32* ob, u32* oneed, u32* ocb) {
    u32 cnt[16]; u32 mysum = 0;
#pragma unroll
    for (int i = 0; i < 8; ++i) {
      u32 pk = hist[tid * 8 + i];
      u32 c0 = pk & 0xFFFFu, c1 = pk >> 16;
      cnt[2 * i] = c0; cnt[2 * i + 1] = c1; mysum += c0 + c1;
    }
    tsum[tid] = mysum;
    __syncthreads();
    if (tid < 64) {
      u32 s0 = tsum[tid * 4], s1 = tsum[tid * 4 + 1];
      u32 s2 = tsum[tid * 4 + 2], s3 = tsum[tid * 4 + 3];
      u32 lsum = s0 + s1 + s2 + s3;
      u32 suf = lsum;
#pragma unroll
      for (int d = 1; d < 64; d <<= 1) {
        u32 v = (u32)__shfl_down((int)suf, d);
        if (tid + d < 64) suf += v;
      }
      u32 above = suf - lsum;             // strictly-higher lanes
      tabove[tid * 4 + 3] = above;
      tabove[tid * 4 + 2] = above + s3;
      tabove[tid * 4 + 1] = above + s3 + s2;
      tabove[tid * 4 + 0] = above + s3 + s2 + s1;
    }
    __syncthreads();
    u32 above = tabove[tid];
#pragma unroll
    for (int b = 15; b >= 0; --b) {
      u32 c = cnt[b];
      if (above < needK && above + c >= needK) {
        *ob = (u32)(tid * 16 + b); *oneed = needK - above; *ocb = c;
      }
      above += c;
    }
    __syncthreads();
  };
  scan12(KTOP, &s_b, &s_need, &s_cb);

  const u32 b1 = s_b;
  const u32 need1 = s_need, cb1 = s_cb;
  const bool two = (cb1 > EQCAP);     // block-uniform
  u32 b2v = 0, needF = need1;
  if (two) {                          // safety level; ~never taken
    for (int i = tid; i < 2048; i += 256) hist[i] = 0u;
    __syncthreads();
#pragma unroll
    for (int j = 0; j < 32; ++j) {
      u32 k = keys[j];
      if ((k >> 20) == b1) {
        u32 bin = (k >> 8) & 0xFFFu;
        atomicAdd(&hist[bin >> 1], (bin & 1) ? 0x10000u : 1u);
      }
    }
    __syncthreads();
    scan12(need1, &s_b2, &s_need2, &s_cb2);
    b2v = s_b2; needF = s_need2;
  }

  // ---- collect: strictly-greater (<=99) and boundary-equal sets ----
#pragma unroll
  for (int j = 0; j < 32; ++j) {
    u32 k = keys[j];
    u32 hi12 = k >> 20;
    bool g = hi12 > b1, e = (hi12 == b1);
    if (two) {
      u32 mid = (k >> 8) & 0xFFFu;
      g = g || (e && mid > b2v);
      e = e && (mid == b2v);
    }
    if (g) { u32 p = atomicAdd(&s_cg, 1u); if (p < 128u) grbuf[p] = k; }
    else if (e) { u32 p = atomicAdd(&s_ce, 1u); if (p < EQCAP) eqbuf[p] = k; }
  }
  __syncthreads();

  const u32 cg = s_cg;                        // == KTOP - needF
  const u32 ce = min(s_ce, (u32)EQCAP);
  const bool small = (ce <= 128u);            // block-uniform

  // in-register 128-element cross-lane bitonic (2 elems/lane, wave0 only)
  auto sortnet = [&](u32& a, u32& b, bool asc) {
    const int lane = tid;
    for (int k = 2; k <= 128; k <<= 1) {
      for (int j = k >> 1; j > 0; j >>= 1) {
        if (j == 64) {
          bool up = ((lane & k) == 0) == asc;
          u32 lo = min(a, b), hi = max(a, b);
          a = up ? lo : hi;  b = up ? hi : lo;
        } else {
          bool upa = ((lane & k) == 0) == asc;
          bool upb = (((lane + 64) & k) == 0) == asc;
          bool lowa = (lane & j) == 0;
          u32 oa = (u32)__shfl_xor((int)a, j);
          u32 ob = (u32)__shfl_xor((int)b, j);
          a = (lowa == upa) ? min(a, oa) : max(a, oa);
          b = (lowa == upb) ? min(b, ob) : max(b, ob);
        }
      }
    }
  };

  // phase 1: sort the equal set descending (common, small path)
  if (tid < 64 && small) {
    u32 e0 = (tid < (int)ce) ? eqbuf[tid] : PADK;
    u32 e1 = (tid + 64 < (int)ce) ? eqbuf[tid + 64] : PADK;
    sortnet(e0, e1, false);                   // descending
    eqbuf[tid] = e0; eqbuf[tid + 64] = e1;    // eqbuf[0..need) = top need
  }
  __syncthreads();

  if (tid < 64) {
    if (!small) {
      // rare: selection of needF maxima from eqbuf -> grbuf[cg..]
      for (u32 itn = 0; itn < needF; ++itn) {
        u32 mx = 0u;
        for (u32 i = tid; i < ce; i += 64) mx = max(mx, eqbuf[i]);
#pragma unroll
        for (int d = 32; d > 0; d >>= 1) mx = max(mx, (u32)__shfl_xor((int)mx, d));
        u32 fidx = 0xFFFFFFFFu;
        for (u32 i = tid; i < ce; i += 64) if (eqbuf[i] == mx) fidx = min(fidx, i);
#pragma unroll
        for (int d = 32; d > 0; d >>= 1) fidx = min(fidx, (u32)__shfl_xor((int)fidx, d));
        if (tid == (int)(fidx & 63u)) eqbuf[fidx] = 0u;   // clear first occurrence
        if (tid == 0) grbuf[cg + itn] = mx;
      }
    }
    // build merged 128 = greater ++ top-need equal ++ pads, sort ascending
    int i0 = tid, i1 = tid + 64;
    u32 m0, m1;
    if (small) {
      m0 = (i0 < (int)cg) ? grbuf[i0] : ((i0 < KTOP) ? eqbuf[i0 - cg] : PADK);
      m1 = (i1 < (int)cg) ? grbuf[i1] : ((i1 < KTOP) ? eqbuf[i1 - cg] : PADK);
    } else {
      m0 = (i0 < KTOP) ? grbuf[i0] : PADK;
      m1 = (i1 < KTOP) ? grbuf[i1] : PADK;
    }
    sortnet(m0, m1, true);                    // ascending; slots 28..127 = A1
    float s = 0.f;
    if (i0 >= 28) {
      float a1 = float_of_key(m0);
      int t = i0 - 28;
      s += a1 * WA_w[t] + a1 * a1 * WA_w[KTOP + t];
    }
    {
      float a1 = float_of_key(m1);
      int t = i1 - 28;                        // always >= 36
      s += a1 * WA_w[t] + a1 * a1 * WA_w[KTOP + t];
    }
#pragma unroll
    for (int d = 32; d > 0; d >>= 1) s += __shfl_xor(s, d);
    if (tid == 0) Acmb[row_base + (int)blockIdx.x] = -(s + WA_b[0]);
  }
}

// ============================================================
// Threshold (rank select) + softmax over N -> Aw in out[1..N]
// ============================================================
__global__ __launch_bounds__(1024) void thr_softmax(
    const float* __restrict__ Acmb, float* __restrict__ out)
{
  __shared__ float vals[NTOK];
  __shared__ unsigned hist[256];
  __shared__ unsigned sufs[256];
  __shared__ float red[1024];
  __shared__ unsigned s_prefix, s_need;
  const int tid = threadIdx.x;
#pragma unroll
  for (int s = 0; s < 8; ++s) vals[tid + s * 1024] = Acmb[tid + s * 1024];
  if (tid == 0) { s_prefix = 0u; s_need = KTH_RANK; }
  __syncthreads();

  for (int pass = 3; pass >= 0; --pass) {
    if (tid < 256) hist[tid] = 0u;
    __syncthreads();
    unsigned pref  = s_prefix;
    unsigned pmask = (pass == 3) ? 0u : (0xFFFFFFFFu << ((pass + 1) * 8));
#pragma unroll
    for (int s = 0; s < 8; ++s) {
      unsigned key = key_of(vals[tid + s * 1024]);
      if ((key & pmask) == pref)
        atomicAdd(&hist[(key >> (pass * 8)) & 255u], 1u);
    }
    __syncthreads();
    if (tid < 256) sufs[tid] = hist[tid];
    __syncthreads();
    for (int off = 1; off < 256; off <<= 1) {
      unsigned add = 0u;
      if (tid < 256 && tid + off < 256) add = sufs[tid + off];
      __syncthreads();
      if (tid < 256) sufs[tid] += add;
      __syncthreads();
    }
    unsigned need = s_need;
    __syncthreads();
    if (tid < 256) {
      unsigned above = (tid == 255) ? 0u : sufs[tid + 1];
      if (sufs[tid] >= need && above < need) {
        s_prefix = pref | ((unsigned)tid << (pass * 8));
        s_need   = need - above;
      }
    }
    __syncthreads();
  }
  const float thre = float_of_key(s_prefix);

  float loc[8]; float mx = -1e30f;
#pragma unroll
  for (int s = 0; s < 8; ++s) {
    float v = vals[tid + s * 1024];
    v = (v > thre) ? v : 0.0f;
    loc[s] = v; mx = fmaxf(mx, v);
  }
  red[tid] = mx; __syncthreads();
  for (int off = 512; off > 0; off >>= 1) {
    if (tid < off) red[tid] = fmaxf(red[tid], red[tid + off]);
    __syncthreads();
  }
  float m = red[0]; __syncthreads();
  float sm = 0.0f;
#pragma unroll
  for (int s = 0; s < 8; ++s) sm += expf(loc[s] - m);
  red[tid] = sm; __syncthreads();
  for (int off = 512; off > 0; off >>= 1) {
    if (tid < off) red[tid] += red[tid + off];
    __syncthreads();
  }
  float Z = red[0];
#pragma unroll
  for (int s = 0; s < 8; ++s)
    out[1 + tid + s * 1024] = expf(loc[s] - m) / Z;
}

// ============================================================
__global__ __launch_bounds__(256) void z_partial(
    const float* __restrict__ aw, const float* __restrict__ query,
    float* __restrict__ zpart)
{
  const int g = blockIdx.x, t = threadIdx.x;
  float a0 = 0.f, a1 = 0.f;
  for (int r = 0; r < 64; ++r) {
    int n = g * 64 + r;
    float w = aw[n];
    const float* q = query + (size_t)n * HDIM;
    a0 = fmaf(w, q[t],       a0);
    a1 = fmaf(w, q[t + 256], a1);
  }
  zpart[(size_t)g * HDIM + t]       = a0;
  zpart[(size_t)g * HDIM + t + 256] = a1;
}

__global__ __launch_bounds__(512) void finalize(
    const float* __restrict__ zpart, const float* __restrict__ cls_w,
    const float* __restrict__ cls_b, float* __restrict__ out)
{
  __shared__ float red[512];
  const int t = threadIdx.x;
  float s = 0.f;
  for (int g = 0; g < 128; ++g) s += zpart[(size_t)g * HDIM + t];
  red[t] = s * cls_w[t];
  __syncthreads();
  for (int off = 256; off > 0; off >>= 1) {
    if (t < off) red[t] += red[t + off];
    __syncthreads();
  }
  if (t == 0) out[0] = red[0] + cls_b[0];
}

// ============================================================
extern "C" void kernel_launch(void* const* d_in, const int* in_sizes, int n_in,
                              void* d_out, int out_size, void* d_ws, size_t ws_size,
                              hipStream_t stream) {
  (void)in_sizes; (void)n_in; (void)out_size; (void)ws_size;
  const float* x_q   = (const float*)d_in[0];
  const float* x_k   = (const float*)d_in[1];
  const float* WQ_w  = (const float*)d_in[2];
  const float* WQ_b  = (const float*)d_in[3];
  const float* WK_w  = (const float*)d_in[4];
  const float* WK_b  = (const float*)d_in[5];
  const float* WA_w  = (const float*)d_in[6];
  const float* WA_b  = (const float*)d_in[7];
  const float* cls_w = (const float*)d_in[8];
  const float* cls_b = (const float*)d_in[9];
  float* out = (float*)d_out;
  char* base = (char*)d_ws;
  const size_t MB = 1u << 20;

  float* query = (float*)(base);               // 0..16 fp32 tanh(xWq+b)
  u16* qh      = (u16*)(base + 16 * MB);
  u16* ql      = (u16*)(base + 24 * MB);
  u16* kh      = (u16*)(base + 32 * MB);
  u16* kl      = (u16*)(base + 40 * MB);
  u16* xs_hi   = (u16*)(base + 48 * MB);
  u16* xs_lo   = (u16*)(base + 64 * MB);
  float* Ach   = (float*)(base + 80 * MB);     // 64 MB A chunk
  u16* wt_hi   = (u16*)(base + 144 * MB);
  u16* wt_lo   = (u16*)(base + 145 * MB);
  float* rq    = (float*)(base + 146 * MB);
  float* rk    = (float*)(base + 146 * MB + 65536);
  float* Acmb  = (float*)(base + 147 * MB);
  float* zpart = (float*)(base + 147 * MB + 65536);

  dim3 b256(256), b512(512);
  dim3 gproj(HDIM / 128, NTOK / 64);
  dim3 gchunk(NTOK / 128, CHUNK / 128);

  wt_cast<<<dim3(16, 32), b256, 0, stream>>>(WQ_w, wt_hi, wt_lo);
  xsplit<<<2048, b256, 0, stream>>>(x_q, xs_hi, xs_lo);
  gemm_hl<1, 2><<<gproj, b512, 0, stream>>>(xs_hi, xs_lo, wt_hi, wt_lo,
      query, qh, ql, WQ_b, nullptr, nullptr, DIM, HDIM);
  wt_cast<<<dim3(16, 32), b256, 0, stream>>>(WK_w, wt_hi, wt_lo);
  xsplit<<<2048, b256, 0, stream>>>(x_k, xs_hi, xs_lo);
  gemm_hl<2, 2><<<gproj, b512, 0, stream>>>(xs_hi, xs_lo, wt_hi, wt_lo,
      nullptr, kh, kl, WK_b, nullptr, nullptr, DIM, HDIM);
  rownorm_inv<<<4096, b256, 0, stream>>>(qh, ql, kh, kl, rq, rk);
  for (int c = 0; c < NTOK / CHUNK; ++c) {
    gemm_hl<0, 4><<<gchunk, b512, 0, stream>>>(
        qh + (size_t)c * CHUNK * HDIM, ql + (size_t)c * CHUNK * HDIM,
        kh, kl, Ach, nullptr, nullptr, nullptr, rq + c * CHUNK, rk, HDIM, NTOK);
    topk_acmb<<<CHUNK, b256, 0, stream>>>(Ach, WA_w, WA_b, Acmb, c * CHUNK);
  }
  thr_softmax<<<1, dim3(1024), 0, stream>>>(Acmb, out);
  z_partial<<<128, b256, 0, stream>>>(out + 1, query, zpart);
  finalize<<<1, dim3(512), 0, stream>>>(zpart, cls_w, cls_b, out);
}

// Round 8
// 563.933 us; speedup vs baseline: 1.4823x; 1.0081x over previous
//
#include <hip/hip_runtime.h>
#include <hip/hip_bf16.h>
#include <math.h>

#define NTOK 8192
#define DIM  1024
#define HDIM 512
#define KTOP 100
#define CHUNK 4096
#define KTH_RANK 2457   // threshold = 2457th-largest of Acmb == sort_asc[5735]
#define EQCAP 2048
#define PADK 0x3FFFFFFFu   // key_of(-2.0f): below every real key (|A|<=1)

typedef float f32x4 __attribute__((ext_vector_type(4)));
typedef short bf16x8 __attribute__((ext_vector_type(8)));
typedef unsigned int u32;
typedef unsigned short u16;

// ---- monotone float<->uint key (order-preserving) ----
__device__ __forceinline__ unsigned key_of(float f) {
  unsigned u = __float_as_uint(f);
  return (u & 0x80000000u) ? ~u : (u | 0x80000000u);
}
__device__ __forceinline__ float float_of_key(unsigned key) {
  unsigned u = (key & 0x80000000u) ? (key ^ 0x80000000u) : ~key;
  return __uint_as_float(u);
}
// ---- bf16 round-to-nearest-even helpers ----
__device__ __forceinline__ u16 bf16_rn(float x) {
  unsigned u = __float_as_uint(x);
  return (u16)((u + 0x7FFFu + ((u >> 16) & 1u)) >> 16);
}
__device__ __forceinline__ float bf16f(u16 h) {
  return __uint_as_float(((unsigned)h) << 16);
}
// ---- async global->LDS 16B ----
__device__ __forceinline__ void gload16(const void* gptr, void* lptr) {
  __builtin_amdgcn_global_load_lds(
      (const __attribute__((address_space(1))) u32*)gptr,
      (__attribute__((address_space(3))) u32*)lptr, 16, 0, 0);
}

// ============================================================
// Unified split-bf16 NT GEMM, 2-phase double-buffered, BK=32.
// C = (Ahi+Alo).(Bhi+Blo)^T, A/B k-contiguous bf16 hi/lo pairs.
// 512 thr (8 waves 2x4), wave tile (FM*16) x 32, tile BM=FM*32 x 128.
// LDS rows are 64B (32 shorts).  XOR swizzle quad ^= ((row>>1)&3):
// rows alternate 128B-line halves (64B stride), so within a half the
// 8 rows map quads {0,1,2,3}x2 -> 2 lanes/bank-slot = conflict-free
// (the old (row&3) gave {0,2}x4 = 4-way).  Applied on BOTH the
// pre-swizzled global source (linear gload_lds dest) and frag reads.
// MODE 0: Cf = acc * rq[row]*rk[col]   (A-GEMM with folded normalization)
// MODE 1: t=tanh(acc+bias); Cf=t and Chi/Clo=split(t)   (q projection)
// MODE 2: t=tanh(acc+bias); Chi/Clo=split(t)            (k projection)
// ============================================================
template<int MODE, int FM>
__global__ __launch_bounds__(512, 4) void gemm_hl(
    const u16* __restrict__ Ahi, const u16* __restrict__ Alo,
    const u16* __restrict__ Bhi, const u16* __restrict__ Blo,
    float* __restrict__ Cf, u16* __restrict__ Chi, u16* __restrict__ Clo,
    const float* __restrict__ bias,
    const float* __restrict__ rq, const float* __restrict__ rk,
    int K, int ldc)
{
  constexpr int BM = FM * 32;
  constexpr int RT = 2 * BM + 256;
  constexpr int RPW = RT / 8;
  constexpr int NI = RPW / 16;
  __shared__ __align__(16) short lds[2][RT * 32];

  const int tid = threadIdx.x, lane = tid & 63, wave = tid >> 6;
  const int wm = wave >> 2, wn = wave & 3;

  const int nwg = gridDim.x * gridDim.y;
  const int lin = blockIdx.y * gridDim.x + blockIdx.x;
  const int cpx = nwg >> 3;
  const int swz = (lin & 7) * cpx + (lin >> 3);
  const int bx = swz % gridDim.x, by = swz / gridDim.x;
  const int bm = by * BM, bn = bx * 128;

  f32x4 acc[FM][2] = {};

  auto STAGE = [&](int buf, int k0) {
#pragma unroll
    for (int j = 0; j < NI; ++j) {
      int rg = wave * RPW + j * 16;
      int r  = rg + (lane >> 2);
      const u16* gp; size_t grow;
      if (rg < BM)                { gp = Ahi; grow = (size_t)(bm + r); }
      else if (rg < 2 * BM)       { gp = Alo; grow = (size_t)(bm + r - BM); }
      else if (rg < 2 * BM + 128) { gp = Bhi; grow = (size_t)(bn + r - 2 * BM); }
      else                        { gp = Blo; grow = (size_t)(bn + r - 2 * BM - 128); }
      int ks = k0 + (((lane & 3) ^ ((r >> 1) & 3)) << 3);   // pre-swizzled quad
      gload16(gp + grow * (size_t)K + ks, &lds[buf][rg * 32]);
    }
  };

  STAGE(0, 0);
  __syncthreads();
  const int NT = K / 32;
  int cur = 0;
  for (int t = 0; t < NT; ++t) {
    if (t + 1 < NT) STAGE(cur ^ 1, (t + 1) * 32);
    const short* L = lds[cur];
    const int qb = lane >> 4;
    bf16x8 ah[FM], al[FM], bh[2], bl[2];
#pragma unroll
    for (int m = 0; m < FM; ++m) {
      int r = wm * (FM * 16) + m * 16 + (lane & 15);
      int off = r * 32 + ((qb ^ ((r >> 1) & 3)) << 3);
      ah[m] = *(const bf16x8*)&L[off];
      al[m] = *(const bf16x8*)&L[BM * 32 + off];
    }
#pragma unroll
    for (int n = 0; n < 2; ++n) {
      int r = wn * 32 + n * 16 + (lane & 15);
      int off = r * 32 + ((qb ^ ((r >> 1) & 3)) << 3);
      bh[n] = *(const bf16x8*)&L[2 * BM * 32 + off];
      bl[n] = *(const bf16x8*)&L[(2 * BM + 128) * 32 + off];
    }
#pragma unroll
    for (int n = 0; n < 2; ++n)
#pragma unroll
      for (int m = 0; m < FM; ++m) {
        acc[m][n] = __builtin_amdgcn_mfma_f32_16x16x32_bf16(ah[m], bh[n], acc[m][n], 0, 0, 0);
        acc[m][n] = __builtin_amdgcn_mfma_f32_16x16x32_bf16(ah[m], bl[n], acc[m][n], 0, 0, 0);
        acc[m][n] = __builtin_amdgcn_mfma_f32_16x16x32_bf16(al[m], bh[n], acc[m][n], 0, 0, 0);
      }
    __syncthreads();
    cur ^= 1;
  }

#pragma unroll
  for (int m = 0; m < FM; ++m) {
    int rbase = bm + wm * (FM * 16) + m * 16 + (lane >> 4) * 4;
#pragma unroll
    for (int n = 0; n < 2; ++n) {
      int col = bn + wn * 32 + n * 16 + (lane & 15);
      if (MODE == 0) {
        float cs = rk[col];
#pragma unroll
        for (int r = 0; r < 4; ++r)
          Cf[(size_t)(rbase + r) * ldc + col] = acc[m][n][r] * rq[rbase + r] * cs;
      } else {
        float b = bias[col];
#pragma unroll
        for (int r = 0; r < 4; ++r) {
          size_t idx = (size_t)(rbase + r) * ldc + col;
          float t = tanhf(acc[m][n][r] + b);
          if (MODE == 1) Cf[idx] = t;
          u16 h = bf16_rn(t);
          Chi[idx] = h;
          Clo[idx] = bf16_rn(t - bf16f(h));
        }
      }
    }
  }
}

// ============================================================
__global__ __launch_bounds__(256) void xsplit(
    const float* __restrict__ x, u16* __restrict__ hi, u16* __restrict__ lo)
{
  for (int i = blockIdx.x * 256 + threadIdx.x; i < NTOK * DIM / 4; i += gridDim.x * 256) {
    float4 v = ((const float4*)x)[i];
    ushort4 h, l;
    h.x = bf16_rn(v.x); l.x = bf16_rn(v.x - bf16f(h.x));
    h.y = bf16_rn(v.y); l.y = bf16_rn(v.y - bf16f(h.y));
    h.z = bf16_rn(v.z); l.z = bf16_rn(v.z - bf16f(h.z));
    h.w = bf16_rn(v.w); l.w = bf16_rn(v.w - bf16f(h.w));
    ((ushort4*)hi)[i] = h;
    ((ushort4*)lo)[i] = l;
  }
}

// ============================================================
__global__ __launch_bounds__(256) void wt_cast(
    const float* __restrict__ W, u16* __restrict__ Thi, u16* __restrict__ Tlo)
{
  __shared__ float t[32][33];
  const int bx = blockIdx.x, by = blockIdx.y;
  const int r = threadIdx.x >> 5, c = threadIdx.x & 31;
#pragma unroll
  for (int i = 0; i < 4; ++i)
    t[r + i * 8][c] = W[(size_t)(by * 32 + r + i * 8) * HDIM + bx * 32 + c];
  __syncthreads();
#pragma unroll
  for (int i = 0; i < 4; ++i) {
    int n = bx * 32 + r + i * 8, k = by * 32 + c;
    float v = t[c][r + i * 8];
    u16 h = bf16_rn(v);
    Thi[(size_t)n * DIM + k] = h;
    Tlo[(size_t)n * DIM + k] = bf16_rn(v - bf16f(h));
  }
}

// ============================================================
__global__ __launch_bounds__(256) void rownorm_inv(
    const u16* __restrict__ qh, const u16* __restrict__ ql,
    const u16* __restrict__ kh, const u16* __restrict__ kl,
    float* __restrict__ rq, float* __restrict__ rk)
{
  const int half = blockIdx.x >> 11;
  const int row = (blockIdx.x & 2047) * 4 + (threadIdx.x >> 6);
  const int lane = threadIdx.x & 63;
  const u16* hi = half ? kh : qh;
  const u16* lo = half ? kl : ql;
  size_t base = (size_t)row * HDIM + lane * 8;
  ushort4 h0 = *(const ushort4*)&hi[base], h1 = *(const ushort4*)&hi[base + 4];
  ushort4 l0 = *(const ushort4*)&lo[base], l1 = *(const ushort4*)&lo[base + 4];
  float f[8] = {bf16f(h0.x)+bf16f(l0.x), bf16f(h0.y)+bf16f(l0.y),
                bf16f(h0.z)+bf16f(l0.z), bf16f(h0.w)+bf16f(l0.w),
                bf16f(h1.x)+bf16f(l1.x), bf16f(h1.y)+bf16f(l1.y),
                bf16f(h1.z)+bf16f(l1.z), bf16f(h1.w)+bf16f(l1.w)};
  float ss = 0.f;
#pragma unroll
  for (int j = 0; j < 8; ++j) ss += f[j] * f[j];
#pragma unroll
  for (int off = 32; off > 0; off >>= 1) ss += __shfl_xor(ss, off);
  if (lane == 0) {
    float r = 1.0f / fmaxf(sqrtf(ss), 1e-12f);
    (half ? rk : rq)[row] = r;
  }
}

// ============================================================
// Per-row exact top-100, barrier-minimized (unchanged from round 7).
// ============================================================
__global__ __launch_bounds__(256) void topk_acmb(
    const float* __restrict__ Arows, const float* __restrict__ WA_w,
    const float* __restrict__ WA_b, float* __restrict__ Acmb, int row_base)
{
  __shared__ u32 hist[2048];      // 4096 bins, 2 x 16-bit counts per u32
  __shared__ u32 eqbuf[EQCAP];
  __shared__ u32 grbuf[128];
  __shared__ u32 tsum[256], tabove[256];
  __shared__ u32 s_b, s_need, s_cb, s_b2, s_need2, s_cb2, s_cg, s_ce;

  const int tid = threadIdx.x;
  const float4* src = (const float4*)(Arows + (size_t)blockIdx.x * NTOK);

  for (int i = tid; i < 2048; i += 256) hist[i] = 0u;
  if (tid == 0) { s_cg = 0u; s_ce = 0u; }

  u32 keys[32];
#pragma unroll
  for (int i = 0; i < 8; ++i) {
    float4 v = src[i * 256 + tid];
    keys[i * 4 + 0] = key_of(v.x);
    keys[i * 4 + 1] = key_of(v.y);
    keys[i * 4 + 2] = key_of(v.z);
    keys[i * 4 + 3] = key_of(v.w);
  }
  __syncthreads();

#pragma unroll
  for (int j = 0; j < 32; ++j) {
    u32 bin = keys[j] >> 20;
    atomicAdd(&hist[bin >> 1], (bin & 1) ? 0x10000u : 1u);
  }
  __syncthreads();

  auto scan12 = [&](u32 needK, u32* ob, u32* oneed, u32* ocb) {
    u32 cnt[16]; u32 mysum = 0;
#pragma unroll
    for (int i = 0; i < 8; ++i) {
      u32 pk = hist[tid * 8 + i];
      u32 c0 = pk & 0xFFFFu, c1 = pk >> 16;
      cnt[2 * i] = c0; cnt[2 * i + 1] = c1; mysum += c0 + c1;
    }
    tsum[tid] = mysum;
    __syncthreads();
    if (tid < 64) {
      u32 s0 = tsum[tid * 4], s1 = tsum[tid * 4 + 1];
      u32 s2 = tsum[tid * 4 + 2], s3 = tsum[tid * 4 + 3];
      u32 lsum = s0 + s1 + s2 + s3;
      u32 suf = lsum;
#pragma unroll
      for (int d = 1; d < 64; d <<= 1) {
        u32 v = (u32)__shfl_down((int)suf, d);
        if (tid + d < 64) suf += v;
      }
      u32 above = suf - lsum;
      tabove[tid * 4 + 3] = above;
      tabove[tid * 4 + 2] = above + s3;
      tabove[tid * 4 + 1] = above + s3 + s2;
      tabove[tid * 4 + 0] = above + s3 + s2 + s1;
    }
    __syncthreads();
    u32 above = tabove[tid];
#pragma unroll
    for (int b = 15; b >= 0; --b) {
      u32 c = cnt[b];
      if (above < needK && above + c >= needK) {
        *ob = (u32)(tid * 16 + b); *oneed = needK - above; *ocb = c;
      }
      above += c;
    }
    __syncthreads();
  };
  scan12(KTOP, &s_b, &s_need, &s_cb);

  const u32 b1 = s_b;
  const u32 need1 = s_need, cb1 = s_cb;
  const bool two = (cb1 > EQCAP);
  u32 b2v = 0, needF = need1;
  if (two) {
    for (int i = tid; i < 2048; i += 256) hist[i] = 0u;
    __syncthreads();
#pragma unroll
    for (int j = 0; j < 32; ++j) {
      u32 k = keys[j];
      if ((k >> 20) == b1) {
        u32 bin = (k >> 8) & 0xFFFu;
        atomicAdd(&hist[bin >> 1], (bin & 1) ? 0x10000u : 1u);
      }
    }
    __syncthreads();
    scan12(need1, &s_b2, &s_need2, &s_cb2);
    b2v = s_b2; needF = s_need2;
  }

#pragma unroll
  for (int j = 0; j < 32; ++j) {
    u32 k = keys[j];
    u32 hi12 = k >> 20;
    bool g = hi12 > b1, e = (hi12 == b1);
    if (two) {
      u32 mid = (k >> 8) & 0xFFFu;
      g = g || (e && mid > b2v);
      e = e && (mid == b2v);
    }
    if (g) { u32 p = atomicAdd(&s_cg, 1u); if (p < 128u) grbuf[p] = k; }
    else if (e) { u32 p = atomicAdd(&s_ce, 1u); if (p < EQCAP) eqbuf[p] = k; }
  }
  __syncthreads();

  const u32 cg = s_cg;
  const u32 ce = min(s_ce, (u32)EQCAP);
  const bool small = (ce <= 128u);

  auto sortnet = [&](u32& a, u32& b, bool asc) {
    const int lane = tid;
    for (int k = 2; k <= 128; k <<= 1) {
      for (int j = k >> 1; j > 0; j >>= 1) {
        if (j == 64) {
          bool up = ((lane & k) == 0) == asc;
          u32 lo = min(a, b), hi = max(a, b);
          a = up ? lo : hi;  b = up ? hi : lo;
        } else {
          bool upa = ((lane & k) == 0) == asc;
          bool upb = (((lane + 64) & k) == 0) == asc;
          bool lowa = (lane & j) == 0;
          u32 oa = (u32)__shfl_xor((int)a, j);
          u32 ob = (u32)__shfl_xor((int)b, j);
          a = (lowa == upa) ? min(a, oa) : max(a, oa);
          b = (lowa == upb) ? min(b, ob) : max(b, ob);
        }
      }
    }
  };

  if (tid < 64 && small) {
    u32 e0 = (tid < (int)ce) ? eqbuf[tid] : PADK;
    u32 e1 = (tid + 64 < (int)ce) ? eqbuf[tid + 64] : PADK;
    sortnet(e0, e1, false);
    eqbuf[tid] = e0; eqbuf[tid + 64] = e1;
  }
  __syncthreads();

  if (tid < 64) {
    if (!small) {
      for (u32 itn = 0; itn < needF; ++itn) {
        u32 mx = 0u;
        for (u32 i = tid; i < ce; i += 64) mx = max(mx, eqbuf[i]);
#pragma unroll
        for (int d = 32; d > 0; d >>= 1) mx = max(mx, (u32)__shfl_xor((int)mx, d));
        u32 fidx = 0xFFFFFFFFu;
        for (u32 i = tid; i < ce; i += 64) if (eqbuf[i] == mx) fidx = min(fidx, i);
#pragma unroll
        for (int d = 32; d > 0; d >>= 1) fidx = min(fidx, (u32)__shfl_xor((int)fidx, d));
        if (tid == (int)(fidx & 63u)) eqbuf[fidx] = 0u;
        if (tid == 0) grbuf[cg + itn] = mx;
      }
    }
    int i0 = tid, i1 = tid + 64;
    u32 m0, m1;
    if (small) {
      m0 = (i0 < (int)cg) ? grbuf[i0] : ((i0 < KTOP) ? eqbuf[i0 - cg] : PADK);
      m1 = (i1 < (int)cg) ? grbuf[i1] : ((i1 < KTOP) ? eqbuf[i1 - cg] : PADK);
    } else {
      m0 = (i0 < KTOP) ? grbuf[i0] : PADK;
      m1 = (i1 < KTOP) ? grbuf[i1] : PADK;
    }
    sortnet(m0, m1, true);
    float s = 0.f;
    if (i0 >= 28) {
      float a1 = float_of_key(m0);
      int t = i0 - 28;
      s += a1 * WA_w[t] + a1 * a1 * WA_w[KTOP + t];
    }
    {
      float a1 = float_of_key(m1);
      int t = i1 - 28;
      s += a1 * WA_w[t] + a1 * a1 * WA_w[KTOP + t];
    }
#pragma unroll
    for (int d = 32; d > 0; d >>= 1) s += __shfl_xor(s, d);
    if (tid == 0) Acmb[row_base + (int)blockIdx.x] = -(s + WA_b[0]);
  }
}

// ============================================================
// Threshold (rank select) + softmax over N -> Aw in out[1..N]
// ============================================================
__global__ __launch_bounds__(1024) void thr_softmax(
    const float* __restrict__ Acmb, float* __restrict__ out)
{
  __shared__ float vals[NTOK];
  __shared__ unsigned hist[256];
  __shared__ unsigned sufs[256];
  __shared__ float red[1024];
  __shared__ unsigned s_prefix, s_need;
  const int tid = threadIdx.x;
#pragma unroll
  for (int s = 0; s < 8; ++s) vals[tid + s * 1024] = Acmb[tid + s * 1024];
  if (tid == 0) { s_prefix = 0u; s_need = KTH_RANK; }
  __syncthreads();

  for (int pass = 3; pass >= 0; --pass) {
    if (tid < 256) hist[tid] = 0u;
    __syncthreads();
    unsigned pref  = s_prefix;
    unsigned pmask = (pass == 3) ? 0u : (0xFFFFFFFFu << ((pass + 1) * 8));
#pragma unroll
    for (int s = 0; s < 8; ++s) {
      unsigned key = key_of(vals[tid + s * 1024]);
      if ((key & pmask) == pref)
        atomicAdd(&hist[(key >> (pass * 8)) & 255u], 1u);
    }
    __syncthreads();
    if (tid < 256) sufs[tid] = hist[tid];
    __syncthreads();
    for (int off = 1; off < 256; off <<= 1) {
      unsigned add = 0u;
      if (tid < 256 && tid + off < 256) add = sufs[tid + off];
      __syncthreads();
      if (tid < 256) sufs[tid] += add;
      __syncthreads();
    }
    unsigned need = s_need;
    __syncthreads();
    if (tid < 256) {
      unsigned above = (tid == 255) ? 0u : sufs[tid + 1];
      if (sufs[tid] >= need && above < need) {
        s_prefix = pref | ((unsigned)tid << (pass * 8));
        s_need   = need - above;
      }
    }
    __syncthreads();
  }
  const float thre = float_of_key(s_prefix);

  float loc[8]; float mx = -1e30f;
#pragma unroll
  for (int s = 0; s < 8; ++s) {
    float v = vals[tid + s * 1024];
    v = (v > thre) ? v : 0.0f;
    loc[s] = v; mx = fmaxf(mx, v);
  }
  red[tid] = mx; __syncthreads();
  for (int off = 512; off > 0; off >>= 1) {
    if (tid < off) red[tid] = fmaxf(red[tid], red[tid + off]);
    __syncthreads();
  }
  float m = red[0]; __syncthreads();
  float sm = 0.0f;
#pragma unroll
  for (int s = 0; s < 8; ++s) sm += expf(loc[s] - m);
  red[tid] = sm; __syncthreads();
  for (int off = 512; off > 0; off >>= 1) {
    if (tid < off) red[tid] += red[tid + off];
    __syncthreads();
  }
  float Z = red[0];
#pragma unroll
  for (int s = 0; s < 8; ++s)
    out[1 + tid + s * 1024] = expf(loc[s] - m) / Z;
}

// ============================================================
__global__ __launch_bounds__(256) void z_partial(
    const float* __restrict__ aw, const float* __restrict__ query,
    float* __restrict__ zpart)
{
  const int g = blockIdx.x, t = threadIdx.x;
  float a0 = 0.f, a1 = 0.f;
  for (int r = 0; r < 64; ++r) {
    int n = g * 64 + r;
    float w = aw[n];
    const float* q = query + (size_t)n * HDIM;
    a0 = fmaf(w, q[t],       a0);
    a1 = fmaf(w, q[t + 256], a1);
  }
  zpart[(size_t)g * HDIM + t]       = a0;
  zpart[(size_t)g * HDIM + t + 256] = a1;
}

__global__ __launch_bounds__(512) void finalize(
    const float* __restrict__ zpart, const float* __restrict__ cls_w,
    const float* __restrict__ cls_b, float* __restrict__ out)
{
  __shared__ float red[512];
  const int t = threadIdx.x;
  float s = 0.f;
  for (int g = 0; g < 128; ++g) s += zpart[(size_t)g * HDIM + t];
  red[t] = s * cls_w[t];
  __syncthreads();
  for (int off = 256; off > 0; off >>= 1) {
    if (t < off) red[t] += red[t + off];
    __syncthreads();
  }
  if (t == 0) out[0] = red[0] + cls_b[0];
}

// ============================================================
extern "C" void kernel_launch(void* const* d_in, const int* in_sizes, int n_in,
                              void* d_out, int out_size, void* d_ws, size_t ws_size,
                              hipStream_t stream) {
  (void)in_sizes; (void)n_in; (void)out_size; (void)ws_size;
  const float* x_q   = (const float*)d_in[0];
  const float* x_k   = (const float*)d_in[1];
  const float* WQ_w  = (const float*)d_in[2];
  const float* WQ_b  = (const float*)d_in[3];
  const float* WK_w  = (const float*)d_in[4];
  const float* WK_b  = (const float*)d_in[5];
  const float* WA_w  = (const float*)d_in[6];
  const float* WA_b  = (const float*)d_in[7];
  const float* cls_w = (const float*)d_in[8];
  const float* cls_b = (const float*)d_in[9];
  float* out = (float*)d_out;
  char* base = (char*)d_ws;
  const size_t MB = 1u << 20;

  // ws 256 MiB.  Ach is now 128 MB (CHUNK=4096).
  float* query = (float*)(base);               // 0..16 fp32 tanh(xWq+b)
  u16* qh      = (u16*)(base + 16 * MB);
  u16* ql      = (u16*)(base + 24 * MB);
  u16* kh      = (u16*)(base + 32 * MB);
  u16* kl      = (u16*)(base + 40 * MB);
  u16* xs_hi   = (u16*)(base + 48 * MB);       // dead after projections
  u16* xs_lo   = (u16*)(base + 64 * MB);
  float* Ach   = (float*)(base + 80 * MB);     // 80..208 (128 MB)
  u16* wt_hi   = (u16*)(base + 208 * MB);
  u16* wt_lo   = (u16*)(base + 209 * MB);
  float* rq    = (float*)(base + 210 * MB);
  float* rk    = (float*)(base + 210 * MB + 65536);
  float* Acmb  = (float*)(base + 211 * MB);
  float* zpart = (float*)(base + 211 * MB + 65536);

  dim3 b256(256), b512(512);
  dim3 gproj(HDIM / 128, NTOK / 64);           // 4 x 128 (FM=2)
  dim3 gchunk(NTOK / 128, CHUNK / 128);        // 64 x 32 = 2048 blocks (FM=4)

  wt_cast<<<dim3(16, 32), b256, 0, stream>>>(WQ_w, wt_hi, wt_lo);
  xsplit<<<2048, b256, 0, stream>>>(x_q, xs_hi, xs_lo);
  gemm_hl<1, 2><<<gproj, b512, 0, stream>>>(xs_hi, xs_lo, wt_hi, wt_lo,
      query, qh, ql, WQ_b, nullptr, nullptr, DIM, HDIM);
  wt_cast<<<dim3(16, 32), b256, 0, stream>>>(WK_w, wt_hi, wt_lo);
  xsplit<<<2048, b256, 0, stream>>>(x_k, xs_hi, xs_lo);
  gemm_hl<2, 2><<<gproj, b512, 0, stream>>>(xs_hi, xs_lo, wt_hi, wt_lo,
      nullptr, kh, kl, WK_b, nullptr, nullptr, DIM, HDIM);
  rownorm_inv<<<4096, b256, 0, stream>>>(qh, ql, kh, kl, rq, rk);
  for (int c = 0; c < NTOK / CHUNK; ++c) {
    gemm_hl<0, 4><<<gchunk, b512, 0, stream>>>(
        qh + (size_t)c * CHUNK * HDIM, ql + (size_t)c * CHUNK * HDIM,
        kh, kl, Ach, nullptr, nullptr, nullptr, rq + c * CHUNK, rk, HDIM, NTOK);
    topk_acmb<<<CHUNK, b256, 0, stream>>>(Ach, WA_w, WA_b, Acmb, c * CHUNK);
  }
  thr_softmax<<<1, dim3(1024), 0, stream>>>(Acmb, out);
  z_partial<<<128, b256, 0, stream>>>(out + 1, query, zpart);
  finalize<<<1, dim3(512), 0, stream>>>(zpart, cls_w, cls_b, out);
}